// Round 1
// baseline (88.541 us; speedup 1.0000x reference)
//
#include <hip/hip_runtime.h>
#include <hip/hip_fp16.h>
#include <stdint.h>

#define IN_F    4096
#define OUT_F   11008
#define NBITS   4
#define GROUP   128
#define NGROUPS 32      // IN_F / GROUP
#define NWORDS  128     // IN_F / 32

typedef _Float16 half2_t __attribute__((ext_vector_type(2)));

union U32H2 { uint32_t u; half2_t h; };

// lane = output o (coalesced over o, the fastest dim of qweight/alpha/q_bias)
// wave = one group g; workgroup = 4 waves = 4 consecutive groups
// grid = (OUT_F/64 o-tiles, NGROUPS/4 group-tiles); partials via f32 atomicAdd.
__global__ __launch_bounds__(256, 4)
void lutgemm_kernel(const float* __restrict__ x,
                    const int*   __restrict__ qweight,
                    const float* __restrict__ alpha,
                    const float* __restrict__ qbias,
                    float*       __restrict__ y)
{
    // 16 words (this WG's 4 groups) x 16 interleaved f16 pairs (x[32w+k], x[32w+k+16])
    __shared__ uint32_t sx[256];

    const int lane = threadIdx.x & 63;
    const int wave = threadIdx.x >> 6;          // 0..3
    const int g    = blockIdx.y * 4 + wave;     // group 0..31
    const int o    = blockIdx.x * 64 + lane;    // output index

    // ---- issue all global loads early (16 sign-masks + 4 alpha + qbias) ----
    uint32_t m[4][4];
    const int gw0 = g * 4;                      // first 32-input word of this group
#pragma unroll
    for (int wi = 0; wi < 4; ++wi)
#pragma unroll
        for (int b = 0; b < NBITS; ++b)
            m[wi][b] = (uint32_t)qweight[((gw0 + wi) * NBITS + b) * OUT_F + o];

    float a[NBITS];
#pragma unroll
    for (int b = 0; b < NBITS; ++b)
        a[b] = alpha[(g * NBITS + b) * OUT_F + o];
    const float qb = qbias[g * OUT_F + o];

    // ---- exact f32 group sum S_g = sum_{i in g} x[i] (for the q_bias term) ----
    float2 x2 = ((const float2*)x)[g * 64 + lane];
    float sg = x2.x + x2.y;
#pragma unroll
    for (int off = 32; off > 0; off >>= 1)
        sg += __shfl_xor(sg, off, 64);

    // ---- LDS prep: interleaved f16 pairs for this WG's 16 words ----
    {
        const int t    = threadIdx.x;           // word widx = t>>4, pair k = t&15
        const int widx = t >> 4;
        const int k    = t & 15;
        const int gw   = blockIdx.y * 16 + widx;
        U32H2 u;
        u.h[0] = (_Float16)x[gw * 32 + k];
        u.h[1] = (_Float16)x[gw * 32 + k + 16];
        sx[t] = u.u;
    }
    __syncthreads();

    // ---- main: 3 VALU ops per 2 bits (lshl / and_or / v_dot2_f32_f16) ----
    float p[NBITS] = {0.f, 0.f, 0.f, 0.f};
#pragma unroll
    for (int wi = 0; wi < 4; ++wi) {
        uint32_t xk[16];
        const uint4* sp = (const uint4*)&sx[wave * 64 + wi * 16];
#pragma unroll
        for (int q = 0; q < 4; ++q) {
            uint4 v = sp[q];
            xk[q * 4 + 0] = v.x; xk[q * 4 + 1] = v.y;
            xk[q * 4 + 2] = v.z; xk[q * 4 + 3] = v.w;
        }
#pragma unroll
        for (int b = 0; b < NBITS; ++b) {
            const uint32_t mm = m[wi][b];
#pragma unroll
            for (int k = 0; k < 16; ++k) {
                // bit k -> f16 sign at 15, bit k+16 -> f16 sign at 31
                uint32_t t = mm << (15 - k);
                U32H2 s;  s.u  = (t & 0x80008000u) | 0x3C003C00u; // packed +/-1.0h (bit=1 -> -1)
                U32H2 xp; xp.u = xk[k];
                p[b] = __builtin_amdgcn_fdot2(s.h, xp.h, p[b], false);
            }
        }
    }

    // p[b] = -partial[g,b,o]  (sign convention above), so y += sum_b alpha*(-p) + qb*S_g
    float yc = qb * sg;
#pragma unroll
    for (int b = 0; b < NBITS; ++b)
        yc = __builtin_fmaf(-a[b], p[b], yc);

    unsafeAtomicAdd(&y[o], yc);
}

extern "C" void kernel_launch(void* const* d_in, const int* in_sizes, int n_in,
                              void* d_out, int out_size, void* d_ws, size_t ws_size,
                              hipStream_t stream) {
    const float* x     = (const float*)d_in[0];
    const int*   qw    = (const int*)d_in[1];
    const float* alpha = (const float*)d_in[2];
    const float* qbias = (const float*)d_in[3];
    float*       y     = (float*)d_out;

    hipMemsetAsync(y, 0, OUT_F * sizeof(float), stream);
    dim3 grid(OUT_F / 64, NGROUPS / 4);
    lutgemm_kernel<<<grid, 256, 0, stream>>>(x, qw, alpha, qbias, y);
}

// Round 2
// 87.626 us; speedup vs baseline: 1.0104x; 1.0104x over previous
//
#include <hip/hip_runtime.h>
#include <hip/hip_fp16.h>
#include <stdint.h>

#define IN_F    4096
#define OUT_F   11008
#define NBITS   4
#define GROUP   128
#define NGROUPS 32      // IN_F / GROUP
#define NWORDS  128     // IN_F / 32

typedef _Float16 half2_t __attribute__((ext_vector_type(2)));

union U32H2 { uint32_t u; half2_t h; };

// lane -> 2 adjacent outputs (dwordx2 mask loads); wave = one group g;
// WG = 4 waves = 4 consecutive groups x 128 outputs.
// grid = (OUT_F/128, NGROUPS/4) = 86 x 8 = 688 WGs; partials via f32 atomicAdd.
__global__ __launch_bounds__(256, 4)
void lutgemm_kernel(const float* __restrict__ x,
                    const int*   __restrict__ qweight,
                    const float* __restrict__ alpha,
                    const float* __restrict__ qbias,
                    float*       __restrict__ y)
{
    // 16 words (this WG's 4 groups) x 16 interleaved f16 pairs (x[32w+k], x[32w+k+16])
    __shared__ uint32_t sx[256];

    const int lane = threadIdx.x & 63;
    const int wave = threadIdx.x >> 6;          // 0..3
    const int g    = blockIdx.y * 4 + wave;     // group 0..31
    const int o2   = blockIdx.x * 128 + lane * 2;  // this thread: outputs o2, o2+1

    // ---- issue all global loads early: 16 x dwordx2 sign-masks (+ alpha/qbias) ----
    uint2 m[4][4];                              // .x -> o2, .y -> o2+1
    const int gw0 = g * 4;
#pragma unroll
    for (int wi = 0; wi < 4; ++wi)
#pragma unroll
        for (int b = 0; b < NBITS; ++b)
            m[wi][b] = *(const uint2*)&qweight[(size_t)((gw0 + wi) * NBITS + b) * OUT_F + o2];

    float2 a[NBITS];
#pragma unroll
    for (int b = 0; b < NBITS; ++b)
        a[b] = *(const float2*)&alpha[(size_t)(g * NBITS + b) * OUT_F + o2];
    const float2 qb = *(const float2*)&qbias[(size_t)g * OUT_F + o2];

    // ---- exact f32 group sum S_g = sum_{i in g} x[i] (for the q_bias term) ----
    float2 x2 = ((const float2*)x)[g * 64 + lane];
    float sg = x2.x + x2.y;
#pragma unroll
    for (int off = 32; off > 0; off >>= 1)
        sg += __shfl_xor(sg, off, 64);

    // ---- LDS prep: interleaved f16 pairs for this WG's 16 words ----
    {
        const int t    = threadIdx.x;           // word widx = t>>4, pair k = t&15
        const int widx = t >> 4;
        const int k    = t & 15;
        const int gw   = blockIdx.y * 16 + widx;
        U32H2 u;
        u.h[0] = (_Float16)x[gw * 32 + k];
        u.h[1] = (_Float16)x[gw * 32 + k + 16];
        sx[t] = u.u;
    }
    __syncthreads();

    // ---- main: per (wi,b,k): 2 shifts + 2 and_or + 2 dot2 for 4 MACs (2 outs) ----
    float p0[NBITS] = {0.f, 0.f, 0.f, 0.f};
    float p1[NBITS] = {0.f, 0.f, 0.f, 0.f};
#pragma unroll
    for (int wi = 0; wi < 4; ++wi) {
        const uint4* sp = (const uint4*)&sx[wave * 64 + wi * 16];
        uint4 v0 = sp[0], v1 = sp[1], v2 = sp[2], v3 = sp[3];
#pragma unroll
        for (int b = 0; b < NBITS; ++b) {
            const uint32_t mm0 = m[wi][b].x;
            const uint32_t mm1 = m[wi][b].y;
#define STEP(K, XW)                                                          \
            {                                                                \
                uint32_t t0 = mm0 << (15 - (K));                             \
                uint32_t t1 = mm1 << (15 - (K));                             \
                U32H2 s0; s0.u = (t0 & 0x80008000u) | 0x3C003C00u;           \
                U32H2 s1; s1.u = (t1 & 0x80008000u) | 0x3C003C00u;           \
                U32H2 xp; xp.u = (XW);                                       \
                p0[b] = __builtin_amdgcn_fdot2(s0.h, xp.h, p0[b], false);    \
                p1[b] = __builtin_amdgcn_fdot2(s1.h, xp.h, p1[b], false);    \
            }
            STEP(0,  v0.x) STEP(1,  v0.y) STEP(2,  v0.z) STEP(3,  v0.w)
            STEP(4,  v1.x) STEP(5,  v1.y) STEP(6,  v1.z) STEP(7,  v1.w)
            STEP(8,  v2.x) STEP(9,  v2.y) STEP(10, v2.z) STEP(11, v2.w)
            STEP(12, v3.x) STEP(13, v3.y) STEP(14, v3.z) STEP(15, v3.w)
#undef STEP
        }
    }

    // p = -partial (bit=1 -> -1 convention), so y += sum_b alpha * (-p) + qb * S_g
    float yc0 = qb.x * sg;
    float yc1 = qb.y * sg;
#pragma unroll
    for (int b = 0; b < NBITS; ++b) {
        yc0 = __builtin_fmaf(-a[b].x, p0[b], yc0);
        yc1 = __builtin_fmaf(-a[b].y, p1[b], yc1);
    }

    unsafeAtomicAdd(&y[o2],     yc0);
    unsafeAtomicAdd(&y[o2 + 1], yc1);
}

extern "C" void kernel_launch(void* const* d_in, const int* in_sizes, int n_in,
                              void* d_out, int out_size, void* d_ws, size_t ws_size,
                              hipStream_t stream) {
    const float* x     = (const float*)d_in[0];
    const int*   qw    = (const int*)d_in[1];
    const float* alpha = (const float*)d_in[2];
    const float* qbias = (const float*)d_in[3];
    float*       y     = (float*)d_out;

    hipMemsetAsync(y, 0, OUT_F * sizeof(float), stream);
    dim3 grid(OUT_F / 128, NGROUPS / 4);
    lutgemm_kernel<<<grid, 256, 0, stream>>>(x, qw, alpha, qbias, y);
}

// Round 3
// 87.616 us; speedup vs baseline: 1.0106x; 1.0001x over previous
//
#include <hip/hip_runtime.h>
#include <hip/hip_fp16.h>
#include <stdint.h>

#define IN_F    4096
#define OUT_F   11008
#define NBITS   4
#define GROUP   128
#define NGROUPS 32      // IN_F / GROUP
#define NWORDS  128     // IN_F / 32

typedef _Float16 half2_t __attribute__((ext_vector_type(2)));

union U32H2 { uint32_t u; half2_t h; };

// WG = 1 wave (64 threads) = 1 group x 128 outputs (2 per lane, dwordx2 loads).
// grid = (OUT_F/128, NGROUPS) = 86 x 32 = 2752 WGs -> 10.75 waves/CU, ~2% tail.
// Partials combined via native f32 atomicAdd (32 contenders per y[o]).
__global__ __launch_bounds__(64)
void lutgemm_kernel(const float* __restrict__ x,
                    const int*   __restrict__ qweight,
                    const float* __restrict__ alpha,
                    const float* __restrict__ qbias,
                    float*       __restrict__ y)
{
    // 4 words (this group's) x 16 interleaved f16 pairs (x[32w+k], x[32w+k+16])
    __shared__ uint32_t sx[64];

    const int lane = threadIdx.x;               // 0..63
    const int g    = blockIdx.y;                // group 0..31
    const int o2   = blockIdx.x * 128 + lane * 2;  // this thread: outputs o2, o2+1

    // ---- issue all global loads early: 16 x dwordx2 sign-masks (+ alpha/qbias) ----
    uint2 m[4][4];                              // .x -> o2, .y -> o2+1
    const int gw0 = g * 4;
#pragma unroll
    for (int wi = 0; wi < 4; ++wi)
#pragma unroll
        for (int b = 0; b < NBITS; ++b)
            m[wi][b] = *(const uint2*)&qweight[(size_t)((gw0 + wi) * NBITS + b) * OUT_F + o2];

    float2 a[NBITS];
#pragma unroll
    for (int b = 0; b < NBITS; ++b)
        a[b] = *(const float2*)&alpha[(size_t)(g * NBITS + b) * OUT_F + o2];
    const float2 qb = *(const float2*)&qbias[(size_t)g * OUT_F + o2];

    // ---- exact f32 group sum S_g = sum_{i in g} x[i] (for the q_bias term) ----
    float2 x2 = ((const float2*)x)[g * 64 + lane];
    float sg = x2.x + x2.y;
#pragma unroll
    for (int off = 32; off > 0; off >>= 1)
        sg += __shfl_xor(sg, off, 64);

    // ---- LDS prep: one interleaved f16 pair per thread (4 words x 16 pairs) ----
    {
        const int widx = lane >> 4;             // word within group, 0..3
        const int k    = lane & 15;             // pair index, 0..15
        const int gw   = gw0 + widx;
        U32H2 u;
        u.h[0] = (_Float16)x[gw * 32 + k];
        u.h[1] = (_Float16)x[gw * 32 + k + 16];
        sx[lane] = u.u;
    }
    __syncthreads();

    // ---- main: per (wi,b,k): 2 shifts + 2 and_or + 2 dot2 for 4 MACs (2 outs) ----
    float p0[NBITS] = {0.f, 0.f, 0.f, 0.f};
    float p1[NBITS] = {0.f, 0.f, 0.f, 0.f};
#pragma unroll
    for (int wi = 0; wi < 4; ++wi) {
        const uint4* sp = (const uint4*)&sx[wi * 16];  // wave-uniform -> LDS broadcast
        uint4 v0 = sp[0], v1 = sp[1], v2 = sp[2], v3 = sp[3];
#pragma unroll
        for (int b = 0; b < NBITS; ++b) {
            const uint32_t mm0 = m[wi][b].x;
            const uint32_t mm1 = m[wi][b].y;
#define STEP(K, XW)                                                          \
            {                                                                \
                uint32_t t0 = mm0 << (15 - (K));                             \
                uint32_t t1 = mm1 << (15 - (K));                             \
                U32H2 s0; s0.u = (t0 & 0x80008000u) | 0x3C003C00u;           \
                U32H2 s1; s1.u = (t1 & 0x80008000u) | 0x3C003C00u;           \
                U32H2 xp; xp.u = (XW);                                       \
                p0[b] = __builtin_amdgcn_fdot2(s0.h, xp.h, p0[b], false);    \
                p1[b] = __builtin_amdgcn_fdot2(s1.h, xp.h, p1[b], false);    \
            }
            STEP(0,  v0.x) STEP(1,  v0.y) STEP(2,  v0.z) STEP(3,  v0.w)
            STEP(4,  v1.x) STEP(5,  v1.y) STEP(6,  v1.z) STEP(7,  v1.w)
            STEP(8,  v2.x) STEP(9,  v2.y) STEP(10, v2.z) STEP(11, v2.w)
            STEP(12, v3.x) STEP(13, v3.y) STEP(14, v3.z) STEP(15, v3.w)
#undef STEP
        }
    }

    // p = -partial (bit=1 -> -1 convention), so y += sum_b alpha * (-p) + qb * S_g
    float yc0 = qb.x * sg;
    float yc1 = qb.y * sg;
#pragma unroll
    for (int b = 0; b < NBITS; ++b) {
        yc0 = __builtin_fmaf(-a[b].x, p0[b], yc0);
        yc1 = __builtin_fmaf(-a[b].y, p1[b], yc1);
    }

    unsafeAtomicAdd(&y[o2],     yc0);
    unsafeAtomicAdd(&y[o2 + 1], yc1);
}

extern "C" void kernel_launch(void* const* d_in, const int* in_sizes, int n_in,
                              void* d_out, int out_size, void* d_ws, size_t ws_size,
                              hipStream_t stream) {
    const float* x     = (const float*)d_in[0];
    const int*   qw    = (const int*)d_in[1];
    const float* alpha = (const float*)d_in[2];
    const float* qbias = (const float*)d_in[3];
    float*       y     = (float*)d_out;

    hipMemsetAsync(y, 0, OUT_F * sizeof(float), stream);
    dim3 grid(OUT_F / 128, NGROUPS);
    lutgemm_kernel<<<grid, 64, 0, stream>>>(x, qw, alpha, qbias, y);
}